// Round 1
// baseline (330.630 us; speedup 1.0000x reference)
//
#include <hip/hip_runtime.h>
#include <stdint.h>

typedef short short8 __attribute__((ext_vector_type(8)));
typedef float f32x4 __attribute__((ext_vector_type(4)));

#define TILE 128
#define LDSS 136   // 128 + 8 bf16 pad: rows stay 16B-aligned, only 2-way bank alias (free, m136)

__device__ __forceinline__ unsigned short f32_to_bf16(float f) {
    uint32_t u = __builtin_bit_cast(uint32_t, f);
    u += 0x7FFFu + ((u >> 16) & 1u);   // RNE; data has no NaNs
    return (unsigned short)(u >> 16);
}
__device__ __forceinline__ float bf16_to_f32(unsigned short h) {
    return __builtin_bit_cast(float, (uint32_t)h << 16);
}

// MODE 0: write preds, accumulate sum((pred-y)^2) into acc[0]
// MODE 1: accumulate sum(alpha[i]*pred[i]) into acc[0]  (K_MM regularizer path)
template<int MODE>
__global__ __launch_bounds__(256, 2)
void rbf_mmv(const float* __restrict__ A, int Arows,
             const float* __restrict__ Yv,
             const float* __restrict__ C, int Mrows,
             const float* __restrict__ alpha,
             const float* __restrict__ sigma,
             float* __restrict__ preds_out,
             float* __restrict__ acc)
{
    __shared__ __align__(16) unsigned short ldsA[TILE * LDSS];
    __shared__ __align__(16) unsigned short ldsC[TILE * LDSS];
    __shared__ float a2p[TILE][2];
    __shared__ float c2p[TILE][2];
    __shared__ float predbuf[TILE][2];

    const int t    = threadIdx.x;
    const int lane = t & 63;
    const int wid  = t >> 6;
    const int wr   = wid >> 1;   // wave row (0..1) -> 64 output rows each
    const int wc   = wid & 1;    // wave col (0..1) -> 64 output cols each
    const int l15  = lane & 15;
    const int quad = lane >> 4;

    const float sig = sigma[0];
    const float q  = 0.7213475204444817f / (sig * sig);  // log2(e)/(2 sigma^2)
    const float q2 = 2.0f * q;

    const int rowbase = blockIdx.x * TILE;

    // ---- stage A tile once: fp32 -> bf16 into LDS, sumsq of ROUNDED values ----
    {
        const int r    = t >> 1;
        const int half = t & 1;
        const int grow = rowbase + r;
        unsigned short* dst = &ldsA[r * LDSS + half * 64];
        float ss = 0.f;
        if (grow < Arows) {
            const float4* src = (const float4*)(A + (size_t)grow * 128 + half * 64);
            #pragma unroll
            for (int k = 0; k < 16; ++k) {
                float4 v = src[k];
                unsigned short h0 = f32_to_bf16(v.x), h1 = f32_to_bf16(v.y);
                unsigned short h2 = f32_to_bf16(v.z), h3 = f32_to_bf16(v.w);
                float f0 = bf16_to_f32(h0), f1 = bf16_to_f32(h1);
                float f2 = bf16_to_f32(h2), f3 = bf16_to_f32(h3);
                ss = fmaf(f0, f0, ss); ss = fmaf(f1, f1, ss);
                ss = fmaf(f2, f2, ss); ss = fmaf(f3, f3, ss);
                uint2 pk;
                pk.x = (uint32_t)h0 | ((uint32_t)h1 << 16);
                pk.y = (uint32_t)h2 | ((uint32_t)h3 << 16);
                *reinterpret_cast<uint2*>(dst + k * 4) = pk;
            }
        } else {
            uint2 z; z.x = 0u; z.y = 0u;
            #pragma unroll
            for (int k = 0; k < 16; ++k)
                *reinterpret_cast<uint2*>(dst + k * 4) = z;
        }
        a2p[r][half] = ss;
    }
    __syncthreads();

    // per-lane row terms: x2[row] * q  (rows this lane owns in MFMA C-layout)
    float rowterm[4][4];
    #pragma unroll
    for (int i = 0; i < 4; ++i) {
        #pragma unroll
        for (int r = 0; r < 4; ++r) {
            int rl = wr * 64 + i * 16 + quad * 4 + r;
            rowterm[i][r] = (a2p[rl][0] + a2p[rl][1]) * q;
        }
    }

    float srow[4][4] = {};   // per-lane running sum over all m of exp(..)*alpha
    const int nm = Mrows / TILE;

    for (int mt = 0; mt < nm; ++mt) {
        __syncthreads();   // protect ldsC/c2p reuse
        // ---- stage C tile ----
        {
            const int r    = t >> 1;
            const int half = t & 1;
            const int grow = mt * TILE + r;    // Mrows % 128 == 0
            unsigned short* dst = &ldsC[r * LDSS + half * 64];
            const float4* src = (const float4*)(C + (size_t)grow * 128 + half * 64);
            float ss = 0.f;
            #pragma unroll
            for (int k = 0; k < 16; ++k) {
                float4 v = src[k];
                unsigned short h0 = f32_to_bf16(v.x), h1 = f32_to_bf16(v.y);
                unsigned short h2 = f32_to_bf16(v.z), h3 = f32_to_bf16(v.w);
                float f0 = bf16_to_f32(h0), f1 = bf16_to_f32(h1);
                float f2 = bf16_to_f32(h2), f3 = bf16_to_f32(h3);
                ss = fmaf(f0, f0, ss); ss = fmaf(f1, f1, ss);
                ss = fmaf(f2, f2, ss); ss = fmaf(f3, f3, ss);
                uint2 pk;
                pk.x = (uint32_t)h0 | ((uint32_t)h1 << 16);
                pk.y = (uint32_t)h2 | ((uint32_t)h3 << 16);
                *reinterpret_cast<uint2*>(dst + k * 4) = pk;
            }
            c2p[r][half] = ss;
        }
        __syncthreads();

        // ---- S = Atile @ Ctile^T for this wave's 64x64 subtile ----
        f32x4 accf[4][4];
        #pragma unroll
        for (int i = 0; i < 4; ++i)
            #pragma unroll
            for (int j = 0; j < 4; ++j)
                accf[i][j] = (f32x4){0.f, 0.f, 0.f, 0.f};

        const unsigned short* pa = &ldsA[(wr * 64 + l15) * LDSS + quad * 8];
        const unsigned short* pb = &ldsC[(wc * 64 + l15) * LDSS + quad * 8];
        #pragma unroll
        for (int kk = 0; kk < 4; ++kk) {
            short8 a[4], b[4];
            #pragma unroll
            for (int i = 0; i < 4; ++i)
                a[i] = *reinterpret_cast<const short8*>(pa + i * 16 * LDSS + kk * 32);
            #pragma unroll
            for (int j = 0; j < 4; ++j)
                b[j] = *reinterpret_cast<const short8*>(pb + j * 16 * LDSS + kk * 32);
            #pragma unroll
            for (int i = 0; i < 4; ++i)
                #pragma unroll
                for (int j = 0; j < 4; ++j)
                    accf[i][j] = __builtin_amdgcn_mfma_f32_16x16x32_bf16(a[i], b[j], accf[i][j], 0, 0, 0);
        }

        // ---- epilogue: exp + alpha-weighted accumulate (registers only) ----
        float colv[4], av[4];
        #pragma unroll
        for (int j = 0; j < 4; ++j) {
            int cl = wc * 64 + j * 16 + l15;
            colv[j] = (c2p[cl][0] + c2p[cl][1]) * q;
            av[j]   = alpha[mt * TILE + cl];
        }
        #pragma unroll
        for (int i = 0; i < 4; ++i) {
            #pragma unroll
            for (int r = 0; r < 4; ++r) {
                float nb = rowterm[i][r];
                #pragma unroll
                for (int j = 0; j < 4; ++j) {
                    float u = fmaf(accf[i][j][r], q2, -(nb + colv[j]));
                    float e = __builtin_amdgcn_exp2f(u);
                    srow[i][r] = fmaf(e, av[j], srow[i][r]);
                }
            }
        }
    }

    // ---- reduce srow over the 16 lanes holding the same row (cols) ----
    #pragma unroll
    for (int i = 0; i < 4; ++i) {
        #pragma unroll
        for (int r = 0; r < 4; ++r) {
            float v = srow[i][r];
            v += __shfl_xor(v, 1);
            v += __shfl_xor(v, 2);
            v += __shfl_xor(v, 4);
            v += __shfl_xor(v, 8);
            if (l15 == 0)
                predbuf[wr * 64 + i * 16 + quad * 4 + r][wc] = v;
        }
    }
    __syncthreads();

    float contrib = 0.f;
    if (t < TILE) {
        int grow = rowbase + t;
        if (grow < Arows) {
            float pred = predbuf[t][0] + predbuf[t][1];
            if (MODE == 0) {
                preds_out[grow] = pred;
                float d = pred - Yv[grow];
                contrib = d * d;
            } else {
                contrib = alpha[grow] * pred;
            }
        }
    }
    contrib += __shfl_xor(contrib, 1);
    contrib += __shfl_xor(contrib, 2);
    contrib += __shfl_xor(contrib, 4);
    contrib += __shfl_xor(contrib, 8);
    contrib += __shfl_xor(contrib, 16);
    contrib += __shfl_xor(contrib, 32);
    if (lane == 0) atomicAdd(acc, contrib);
}

__global__ void finalize_kernel(const float* __restrict__ acc,
                                const float* __restrict__ penalty,
                                float* __restrict__ out, float invN)
{
    if (threadIdx.x == 0) {
        out[0] = acc[0] * invN + __expf(-penalty[0]) * acc[1];
    }
}

extern "C" void kernel_launch(void* const* d_in, const int* in_sizes, int n_in,
                              void* d_out, int out_size, void* d_ws, size_t ws_size,
                              hipStream_t stream) {
    const float* X       = (const float*)d_in[0];
    const float* Y       = (const float*)d_in[1];
    const float* centers = (const float*)d_in[2];
    const float* alpha   = (const float*)d_in[3];
    const float* sigma   = (const float*)d_in[4];
    const float* penalty = (const float*)d_in[5];
    float* out = (float*)d_out;
    float* acc = (float*)d_ws;   // acc[0] = loss sum, acc[1] = reg sum

    const int N = in_sizes[1];   // Y is [N,1]
    const int M = in_sizes[3];   // alpha is [M,1]

    hipMemsetAsync(acc, 0, 2 * sizeof(float), stream);

    const int nblocksA = (N + TILE - 1) / TILE;
    rbf_mmv<0><<<nblocksA, 256, 0, stream>>>(X, N, Y, centers, M, alpha, sigma,
                                             out + 1, acc + 0);
    rbf_mmv<1><<<M / TILE, 256, 0, stream>>>(centers, M, nullptr, centers, M, alpha, sigma,
                                             nullptr, acc + 1);
    finalize_kernel<<<1, 64, 0, stream>>>(acc, penalty, out, 1.0f / (float)N);
}

// Round 2
// 206.103 us; speedup vs baseline: 1.6042x; 1.6042x over previous
//
#include <hip/hip_runtime.h>
#include <stdint.h>

typedef short short8 __attribute__((ext_vector_type(8)));
typedef float f32x4 __attribute__((ext_vector_type(4)));

#define TILE 128

__device__ __forceinline__ unsigned short f32_to_bf16(float f) {
    uint32_t u = __builtin_bit_cast(uint32_t, f);
    u += 0x7FFFu + ((u >> 16) & 1u);   // RNE; data has no NaNs
    return (unsigned short)(u >> 16);
}
__device__ __forceinline__ float bf16_to_f32(unsigned short h) {
    return __builtin_bit_cast(float, (uint32_t)h << 16);
}

// Prep: centers fp32 -> bf16 in MFMA fragment layout, plus cw[m] = {||c||^2 * q, alpha[m]}
// Fragment layout: element (row R, k) -> Bp[(R/16)*2048 + (k/8)*128 + (R%16)*8 + (k%8)]
// so a wave's 16B-per-lane fragment load (lane = quad*16+l15) is contiguous.
__global__ void prep_kernel(const float* __restrict__ C,
                            const float* __restrict__ alpha,
                            const float* __restrict__ sigma,
                            unsigned short* __restrict__ Bp,
                            float2* __restrict__ cw)
{
    const int t = threadIdx.x;
    const int g = blockIdx.x;          // 16-row group
    const int r = t >> 4;              // row within group
    const int c16 = t & 15;            // 8-elem k-chunk
    const int R = g * 16 + r;

    const float4* src = (const float4*)(C + (size_t)R * 128 + c16 * 8);
    float4 va = src[0], vb = src[1];
    unsigned short h[8];
    h[0] = f32_to_bf16(va.x); h[1] = f32_to_bf16(va.y);
    h[2] = f32_to_bf16(va.z); h[3] = f32_to_bf16(va.w);
    h[4] = f32_to_bf16(vb.x); h[5] = f32_to_bf16(vb.y);
    h[6] = f32_to_bf16(vb.z); h[7] = f32_to_bf16(vb.w);
    float ss = 0.f;
    #pragma unroll
    for (int k = 0; k < 8; ++k) {
        float f = bf16_to_f32(h[k]);
        ss = fmaf(f, f, ss);
    }
    uint4 pk;
    pk.x = (uint32_t)h[0] | ((uint32_t)h[1] << 16);
    pk.y = (uint32_t)h[2] | ((uint32_t)h[3] << 16);
    pk.z = (uint32_t)h[4] | ((uint32_t)h[5] << 16);
    pk.w = (uint32_t)h[6] | ((uint32_t)h[7] << 16);
    *reinterpret_cast<uint4*>(Bp + (size_t)g * 2048 + c16 * 128 + r * 8) = pk;

    // reduce ss over the 16 threads of this row (consecutive lanes)
    ss += __shfl_xor(ss, 1);
    ss += __shfl_xor(ss, 2);
    ss += __shfl_xor(ss, 4);
    ss += __shfl_xor(ss, 8);
    if (c16 == 0) {
        float sig = sigma[0];
        float q = 0.7213475204444817f / (sig * sig);  // log2(e)/(2 sigma^2)
        cw[R] = make_float2(ss * q, alpha[R]);
    }
}

// Fused: blocks [0, nA) compute preds + loss-sum over X rows;
//        blocks [nA, nA+M/128) compute the K_MM regularizer sum.
// No barriers in the m-loop: B fragments come straight from the prepped
// global buffer (L2-resident, 512 KB); A fragments from fragment-layout LDS
// (mode 0) or the prepped buffer itself (reg mode).
__global__ __launch_bounds__(256, 2)
void fused_kernel(const float* __restrict__ X, int N,
                  const float* __restrict__ Yv,
                  const unsigned short* __restrict__ Bp,
                  const float2* __restrict__ cw,
                  const float* __restrict__ alpha,
                  const float* __restrict__ sigma,
                  int nA, int nMt,
                  float* __restrict__ preds_out,
                  float* __restrict__ accLoss,
                  float* __restrict__ accReg)
{
    __shared__ __align__(16) unsigned short ldsA[16384];  // 128x128 bf16, fragment layout
    __shared__ float a2p[TILE][2];
    __shared__ float predbuf[TILE][2];

    const int t    = threadIdx.x;
    const int lane = t & 63;
    const int wid  = t >> 6;
    const int wr   = wid >> 1;
    const int wc   = wid & 1;
    const int l15  = lane & 15;
    const int quad = lane >> 4;

    const float sig = sigma[0];
    const float q  = 0.7213475204444817f / (sig * sig);
    const float q2 = 2.0f * q;

    const bool regmode = (int)blockIdx.x >= nA;
    int rowbase;
    float rowterm[4][4];
    const unsigned short* aGlob = nullptr;

    if (!regmode) {
        rowbase = blockIdx.x * TILE;
        // stage X tile: fp32 -> bf16 into fragment-layout LDS + row sumsq
        const int r_   = t >> 1;
        const int half = t & 1;
        const int grow = rowbase + r_;
        unsigned short* dstbase = ldsA + (r_ >> 4) * 2048 + (r_ & 15) * 8;
        float ss = 0.f;
        if (grow < N) {
            const float4* src = (const float4*)(X + (size_t)grow * 128 + half * 64);
            #pragma unroll
            for (int c = 0; c < 8; ++c) {
                float4 va = src[2 * c], vb = src[2 * c + 1];
                unsigned short h0 = f32_to_bf16(va.x), h1 = f32_to_bf16(va.y);
                unsigned short h2 = f32_to_bf16(va.z), h3 = f32_to_bf16(va.w);
                unsigned short h4 = f32_to_bf16(vb.x), h5 = f32_to_bf16(vb.y);
                unsigned short h6 = f32_to_bf16(vb.z), h7 = f32_to_bf16(vb.w);
                float f0 = bf16_to_f32(h0), f1 = bf16_to_f32(h1);
                float f2 = bf16_to_f32(h2), f3 = bf16_to_f32(h3);
                float f4 = bf16_to_f32(h4), f5 = bf16_to_f32(h5);
                float f6 = bf16_to_f32(h6), f7 = bf16_to_f32(h7);
                ss = fmaf(f0, f0, ss); ss = fmaf(f1, f1, ss);
                ss = fmaf(f2, f2, ss); ss = fmaf(f3, f3, ss);
                ss = fmaf(f4, f4, ss); ss = fmaf(f5, f5, ss);
                ss = fmaf(f6, f6, ss); ss = fmaf(f7, f7, ss);
                uint4 pk;
                pk.x = (uint32_t)h0 | ((uint32_t)h1 << 16);
                pk.y = (uint32_t)h2 | ((uint32_t)h3 << 16);
                pk.z = (uint32_t)h4 | ((uint32_t)h5 << 16);
                pk.w = (uint32_t)h6 | ((uint32_t)h7 << 16);
                *reinterpret_cast<uint4*>(dstbase + (half * 8 + c) * 128) = pk;
            }
        } else {
            uint4 z; z.x = z.y = z.z = z.w = 0u;
            #pragma unroll
            for (int c = 0; c < 8; ++c)
                *reinterpret_cast<uint4*>(dstbase + (half * 8 + c) * 128) = z;
        }
        a2p[r_][half] = ss;
        __syncthreads();
        #pragma unroll
        for (int i = 0; i < 4; ++i)
            #pragma unroll
            for (int r = 0; r < 4; ++r) {
                int rl = wr * 64 + i * 16 + quad * 4 + r;
                rowterm[i][r] = (a2p[rl][0] + a2p[rl][1]) * q;
            }
    } else {
        const int b2 = (int)blockIdx.x - nA;
        rowbase = b2 * TILE;
        aGlob = Bp + (size_t)(b2 * 8 + wr * 4) * 2048 + lane * 8;
        #pragma unroll
        for (int i = 0; i < 4; ++i)
            #pragma unroll
            for (int r = 0; r < 4; ++r)
                rowterm[i][r] = cw[rowbase + wr * 64 + i * 16 + quad * 4 + r].x;
    }

    float srow[4][4] = {};

    for (int mt = 0; mt < nMt; ++mt) {
        const unsigned short* bG = Bp + (size_t)(mt * 8 + wc * 4) * 2048 + lane * 8;
        float2 cj[4];
        #pragma unroll
        for (int j = 0; j < 4; ++j)
            cj[j] = cw[mt * TILE + wc * 64 + j * 16 + l15];

        f32x4 accf[4][4];
        #pragma unroll
        for (int i = 0; i < 4; ++i)
            #pragma unroll
            for (int j = 0; j < 4; ++j)
                accf[i][j] = (f32x4){0.f, 0.f, 0.f, 0.f};

        if (!regmode) {
            const unsigned short* aL = ldsA + (size_t)(wr * 4) * 2048 + lane * 8;
            #pragma unroll
            for (int kk = 0; kk < 4; ++kk) {
                short8 a[4], b[4];
                #pragma unroll
                for (int i = 0; i < 4; ++i)
                    a[i] = *reinterpret_cast<const short8*>(aL + i * 2048 + kk * 512);
                #pragma unroll
                for (int j = 0; j < 4; ++j)
                    b[j] = *reinterpret_cast<const short8*>(bG + j * 2048 + kk * 512);
                #pragma unroll
                for (int i = 0; i < 4; ++i)
                    #pragma unroll
                    for (int j = 0; j < 4; ++j)
                        accf[i][j] = __builtin_amdgcn_mfma_f32_16x16x32_bf16(a[i], b[j], accf[i][j], 0, 0, 0);
            }
        } else {
            #pragma unroll
            for (int kk = 0; kk < 4; ++kk) {
                short8 a[4], b[4];
                #pragma unroll
                for (int i = 0; i < 4; ++i)
                    a[i] = *reinterpret_cast<const short8*>(aGlob + i * 2048 + kk * 512);
                #pragma unroll
                for (int j = 0; j < 4; ++j)
                    b[j] = *reinterpret_cast<const short8*>(bG + j * 2048 + kk * 512);
                #pragma unroll
                for (int i = 0; i < 4; ++i)
                    #pragma unroll
                    for (int j = 0; j < 4; ++j)
                        accf[i][j] = __builtin_amdgcn_mfma_f32_16x16x32_bf16(a[i], b[j], accf[i][j], 0, 0, 0);
            }
        }

        // epilogue: u = 2*q*dot - q*x2 - q*c2 ; srow += exp2(u) * alpha
        #pragma unroll
        for (int i = 0; i < 4; ++i) {
            #pragma unroll
            for (int r = 0; r < 4; ++r) {
                float nb = rowterm[i][r];
                #pragma unroll
                for (int j = 0; j < 4; ++j) {
                    float u = fmaf(accf[i][j][r], q2, -(nb + cj[j].x));
                    float e = __builtin_amdgcn_exp2f(u);
                    srow[i][r] = fmaf(e, cj[j].y, srow[i][r]);
                }
            }
        }
    }

    // reduce srow over the 16 lanes holding the same output row
    #pragma unroll
    for (int i = 0; i < 4; ++i) {
        #pragma unroll
        for (int r = 0; r < 4; ++r) {
            float v = srow[i][r];
            v += __shfl_xor(v, 1);
            v += __shfl_xor(v, 2);
            v += __shfl_xor(v, 4);
            v += __shfl_xor(v, 8);
            if (l15 == 0)
                predbuf[wr * 64 + i * 16 + quad * 4 + r][wc] = v;
        }
    }
    __syncthreads();

    float contrib = 0.f;
    if (t < TILE) {
        int grow = rowbase + t;
        if (!regmode) {
            if (grow < N) {
                float pred = predbuf[t][0] + predbuf[t][1];
                preds_out[grow] = pred;
                float d = pred - Yv[grow];
                contrib = d * d;
            }
        } else {
            float pred = predbuf[t][0] + predbuf[t][1];
            contrib = alpha[grow] * pred;
        }
    }
    contrib += __shfl_xor(contrib, 1);
    contrib += __shfl_xor(contrib, 2);
    contrib += __shfl_xor(contrib, 4);
    contrib += __shfl_xor(contrib, 8);
    contrib += __shfl_xor(contrib, 16);
    contrib += __shfl_xor(contrib, 32);
    if (lane == 0) atomicAdd(regmode ? accReg : accLoss, contrib);
}

__global__ void finalize_kernel(const float* __restrict__ acc,
                                const float* __restrict__ penalty,
                                float* __restrict__ out, float invN)
{
    if (threadIdx.x == 0) {
        out[0] = acc[0] * invN + __expf(-penalty[0]) * acc[1];
    }
}

extern "C" void kernel_launch(void* const* d_in, const int* in_sizes, int n_in,
                              void* d_out, int out_size, void* d_ws, size_t ws_size,
                              hipStream_t stream) {
    const float* X       = (const float*)d_in[0];
    const float* Y       = (const float*)d_in[1];
    const float* centers = (const float*)d_in[2];
    const float* alpha   = (const float*)d_in[3];
    const float* sigma   = (const float*)d_in[4];
    const float* penalty = (const float*)d_in[5];
    float* out = (float*)d_out;

    const int N = in_sizes[1];   // Y is [N,1]
    const int M = in_sizes[3];   // alpha is [M,1]

    unsigned short* Bp = (unsigned short*)d_ws;                       // M*128 bf16 = M*256 B
    float2* cw = (float2*)((char*)d_ws + (size_t)M * 256);            // M*8 B
    float* acc = (float*)((char*)d_ws + (size_t)M * 264);             // 2 floats

    hipMemsetAsync(acc, 0, 2 * sizeof(float), stream);

    prep_kernel<<<M / 16, 256, 0, stream>>>(centers, alpha, sigma, Bp, cw);

    const int nA = (N + TILE - 1) / TILE;
    fused_kernel<<<nA + M / TILE, 256, 0, stream>>>(X, N, Y, Bp, cw, alpha, sigma,
                                                    nA, M / TILE, out + 1, acc, acc + 1);

    finalize_kernel<<<1, 64, 0, stream>>>(acc, penalty, out, 1.0f / (float)N);
}